// Round 1
// baseline (121.970 us; speedup 1.0000x reference)
//
#include <hip/hip_runtime.h>

// LinearAttention: B=1, H=16, N=2048, D=DV=64, causal=1, f32 in/out.
// Chunked parallel scan: L=64 chunk, C=32 chunks/head, HC=512 chunk-tasks.
#define Hh   16
#define Nn   2048
#define Dd   64
#define DVv  64
#define Ll   64
#define Cc   (Nn / Ll)      // 32
#define HCc  (Hh * Cc)      // 512
#define EPSf 1e-6f

__device__ __forceinline__ float fmap(float x) {
    // elu(x)+1 = x+1 (x>0) else exp(x)
    return x > 0.0f ? (x + 1.0f) : __expf(x);
}

// ---------------- Phase 1: per-chunk sums S_c = Kf^T V (D x DV), z_c = sum Kf
__global__ __launch_bounds__(256) void k_chunk_sums(
    const float* __restrict__ Kg, const float* __restrict__ Vg,
    float* __restrict__ Sws, float* __restrict__ zws)
{
    __shared__ float sK[Ll * Dd];
    __shared__ float sV[Ll * DVv];
    const int t  = threadIdx.x;
    const int hc = blockIdx.x;                       // h*C + c; chunks are contiguous
    const float* Kc = Kg + (size_t)hc * (Ll * Dd);
    const float* Vc = Vg + (size_t)hc * (Ll * DVv);
    for (int i = t; i < (Ll * Dd) / 4; i += 256) {
        float4 k4 = ((const float4*)Kc)[i];
        float4 v4 = ((const float4*)Vc)[i];
        k4.x = fmap(k4.x); k4.y = fmap(k4.y); k4.z = fmap(k4.z); k4.w = fmap(k4.w);
        ((float4*)sK)[i] = k4;
        ((float4*)sV)[i] = v4;
    }
    __syncthreads();
    const int e = t & 63;              // DV column (lane -> coalesced/stride-1)
    const int dbase = (t >> 6) * 16;   // 16 D-rows per thread (wave-uniform -> LDS broadcast)
    float acc[16];
#pragma unroll
    for (int k = 0; k < 16; ++k) acc[k] = 0.0f;
    for (int m = 0; m < Ll; ++m) {
        float v = sV[m * DVv + e];
#pragma unroll
        for (int k = 0; k < 16; ++k) acc[k] += sK[m * Dd + dbase + k] * v;
    }
    float* So = Sws + (size_t)hc * (Dd * DVv);
#pragma unroll
    for (int k = 0; k < 16; ++k) So[(dbase + k) * DVv + e] = acc[k];
    if (t < Dd) {
        float z = 0.0f;
        for (int m = 0; m < Ll; ++m) z += sK[m * Dd + t];
        zws[hc * Dd + t] = z;
    }
}

// ---------------- Phase 2: in-place EXCLUSIVE prefix over chunk axis per head.
// Parallel over (head, element-group): grid = H*16, each thread owns one of the
// 4096 S-elements (plus group 0 handles z). Independent scans of length C=32.
__global__ __launch_bounds__(256) void k_prefix(
    float* __restrict__ Sws, float* __restrict__ zws)
{
    const int t   = threadIdx.x;
    const int h   = blockIdx.x >> 4;
    const int grp = blockIdx.x & 15;
    const int idx = grp * 256 + t;     // element in [0, 4096)
    float run = 0.0f;
    for (int c = 0; c < Cc; ++c) {
        float* p = Sws + ((size_t)(h * Cc + c)) * (Dd * DVv) + idx;
        float tmp = *p; *p = run; run += tmp;
    }
    if (grp == 0 && t < Dd) {
        float zr = 0.0f;
        for (int c = 0; c < Cc; ++c) {
            float* p = zws + (h * Cc + c) * Dd + t;
            float tmp = *p; *p = zr; zr += tmp;
        }
    }
}

// ---------------- Phase 3: out_n = Qf_n . S_pre + sum_{m<=n} W[n][m] V_m,
//                  den_n  = Qf_n . z_pre + sum_{m<=n} W[n][m];  W = Qf Kf^T.
__global__ __launch_bounds__(256) void k_output(
    const float* __restrict__ Qg, const float* __restrict__ Kg,
    const float* __restrict__ Vg, const float* __restrict__ Spre,
    const float* __restrict__ zpre, float* __restrict__ Og)
{
    __shared__ float sQ[Ll * Dd];      // reused as V after W is built
    __shared__ float sK[Ll * 65];      // +1 pad: lane-varying row reads stride 65
    __shared__ float sW[Ll * 65];
    const int t  = threadIdx.x;
    const int hc = blockIdx.x;
    const float* Qc = Qg + (size_t)hc * (Ll * Dd);
    const float* Kc = Kg + (size_t)hc * (Ll * Dd);
    for (int i = t; i < (Ll * Dd) / 4; i += 256) {
        float4 q4 = ((const float4*)Qc)[i];
        float4 k4 = ((const float4*)Kc)[i];
        const int m = i >> 4;          // row
        const int d = (i & 15) * 4;    // col
        sQ[m * 64 + d + 0] = fmap(q4.x);
        sQ[m * 64 + d + 1] = fmap(q4.y);
        sQ[m * 64 + d + 2] = fmap(q4.z);
        sQ[m * 64 + d + 3] = fmap(q4.w);
        sK[m * 65 + d + 0] = fmap(k4.x);
        sK[m * 65 + d + 1] = fmap(k4.y);
        sK[m * 65 + d + 2] = fmap(k4.z);
        sK[m * 65 + d + 3] = fmap(k4.w);
    }
    __syncthreads();
    const int e     = t & 63;          // DV column (lane)
    const int warp  = t >> 6;
    const int rbase = warp * 16;       // 16 output rows per thread, wave-uniform
    float acc[16], den[16];
#pragma unroll
    for (int k = 0; k < 16; ++k) { acc[k] = 0.0f; den[k] = 0.0f; }

    // Inter-chunk part: acc += Qf . S_pre (read S_pre coalesced from global/L2)
    const float* Sp = Spre + (size_t)hc * (Dd * DVv);
    const float* zp = zpre + hc * Dd;
    for (int d = 0; d < Dd; ++d) {
        float s = Sp[d * DVv + e];
        float z = zp[d];
#pragma unroll
        for (int k = 0; k < 16; ++k) {
            float q = sQ[(rbase + k) * 64 + d];   // wave-uniform broadcast
            acc[k] += q * s;
            den[k] += q * z;
        }
    }

    // W rows [rbase, rbase+16), column m = e (one column per lane)
#pragma unroll 1
    for (int k = 0; k < 16; ++k) {
        const int n = rbase + k;
        float w = 0.0f;
        for (int d = 0; d < Dd; ++d)
            w += sQ[n * 64 + d] * sK[e * 65 + d]; // stride-65: conflict-free
        sW[n * 65 + e] = w;
    }
    __syncthreads();

    // Stage V into sQ's space (sQ no longer needed)
    const float* Vc = Vg + (size_t)hc * (Ll * DVv);
    for (int i = t; i < (Ll * DVv) / 4; i += 256)
        ((float4*)sQ)[i] = ((const float4*)Vc)[i];
    __syncthreads();

    // Intra-chunk, dense tiles m < rbase (trip count wave-uniform)
    for (int m = 0; m < rbase; ++m) {
        float v = sQ[m * 64 + e];
#pragma unroll
        for (int k = 0; k < 16; ++k) {
            float w = sW[(rbase + k) * 65 + m];
            acc[k] += w * v;
            den[k] += w;
        }
    }
    // Diagonal (triangular) tile: m = rbase+j contributes to rows k >= j
#pragma unroll
    for (int j = 0; j < 16; ++j) {
        const int m = rbase + j;
        float v = sQ[m * 64 + e];
#pragma unroll
        for (int k = j; k < 16; ++k) {
            float w = sW[(rbase + k) * 65 + m];
            acc[k] += w * v;
            den[k] += w;
        }
    }

    float* Oc = Og + (size_t)hc * (Ll * DVv);
#pragma unroll
    for (int k = 0; k < 16; ++k)
        Oc[(rbase + k) * DVv + e] = acc[k] / (den[k] + EPSf);
}

extern "C" void kernel_launch(void* const* d_in, const int* in_sizes, int n_in,
                              void* d_out, int out_size, void* d_ws, size_t ws_size,
                              hipStream_t stream) {
    const float* Q = (const float*)d_in[0];
    const float* K = (const float*)d_in[1];
    const float* V = (const float*)d_in[2];
    // causal flag (d_in[3]) is always 1 per setup_inputs; causal path implemented.
    float* Sws = (float*)d_ws;                          // HC * 64*64 floats = 8 MB
    float* zws = Sws + (size_t)HCc * Dd * DVv;          // HC * 64 floats
    float* out = (float*)d_out;

    k_chunk_sums<<<HCc, 256, 0, stream>>>(K, V, Sws, zws);
    k_prefix<<<Hh * 16, 256, 0, stream>>>(Sws, zws);
    k_output<<<HCc, 256, 0, stream>>>(Q, K, V, Sws, zws, out);
}

// Round 2
// 89.497 us; speedup vs baseline: 1.3628x; 1.3628x over previous
//
#include <hip/hip_runtime.h>

// LinearAttention: B=1, H=16, N=2048, D=DV=64, causal=1, f32 in/out.
// Chunked scan, MFMA bf16 for all matmul-shaped work.
#define Hh   16
#define Nn   2048
#define Dd   64
#define DVv  64
#define Ll   64
#define Cc   (Nn / Ll)      // 32
#define HCc  (Hh * Cc)      // 512
#define EPSf 1e-6f
#define LDP  72             // bf16 row stride (+8 pad, keeps 16B align)

typedef __attribute__((ext_vector_type(8))) __bf16 bf16x8;
typedef __attribute__((ext_vector_type(4))) float  f32x4;

__device__ __forceinline__ float fmap(float x) {
    return x > 0.0f ? (x + 1.0f) : __expf(x);   // elu(x)+1
}
__device__ __forceinline__ __bf16 tobf(float x) { return (__bf16)x; }

// ---------------- Phase 1: S_c = Kf^T V (64x64) + z_c = colsum(Kf), via MFMA.
// A = Kf^T (staged transposed), B^T = V^T (staged transposed), extra B row = 1s -> z.
__global__ __launch_bounds__(256) void k_chunk_sums(
    const float* __restrict__ Kg, const float* __restrict__ Vg,
    float* __restrict__ Sws, float* __restrict__ zws)
{
    __shared__ __align__(16) __bf16 sKT[Dd][LDP];   // [d][m]
    __shared__ __align__(16) __bf16 sVT[80][LDP];   // [e][m]; row 64 = ones; 65..79 = 0
    const int t  = threadIdx.x;
    const int hc = blockIdx.x;
    const float4* K4 = (const float4*)(Kg + (size_t)hc * (Ll * Dd));
    const float4* V4 = (const float4*)(Vg + (size_t)hc * (Ll * DVv));
    for (int i = t; i < (Ll * Dd) / 4; i += 256) {   // 4 iters
        float4 k4 = K4[i];
        float4 v4 = V4[i];
        const int m  = i >> 4;
        const int c0 = (i & 15) * 4;
        sKT[c0 + 0][m] = tobf(fmap(k4.x));
        sKT[c0 + 1][m] = tobf(fmap(k4.y));
        sKT[c0 + 2][m] = tobf(fmap(k4.z));
        sKT[c0 + 3][m] = tobf(fmap(k4.w));
        sVT[c0 + 0][m] = tobf(v4.x);
        sVT[c0 + 1][m] = tobf(v4.y);
        sVT[c0 + 2][m] = tobf(v4.z);
        sVT[c0 + 3][m] = tobf(v4.w);
    }
    for (int i = t; i < 16 * LDP; i += 256) {        // aux rows 64..79
        const int r = i / LDP, c = i % LDP;
        sVT[64 + r][c] = (r == 0) ? (__bf16)1.0f : (__bf16)0.0f;
    }
    __syncthreads();

    const int lane = t & 63, wv = t >> 6;
    const int col = lane & 15, quad = lane >> 4;
    float* So = Sws + (size_t)hc * (Dd * DVv);
    // wave wv computes d-rows [wv*16, wv*16+16), 5 e-tiles (tile 4 = z column)
    for (int et = 0; et < 5; ++et) {
        f32x4 acc = {0.f, 0.f, 0.f, 0.f};
#pragma unroll
        for (int ks = 0; ks < 2; ++ks) {
            bf16x8 a = *(const bf16x8*)&sKT[wv * 16 + col][ks * 32 + quad * 8];
            bf16x8 b = *(const bf16x8*)&sVT[et * 16 + col][ks * 32 + quad * 8];
            acc = __builtin_amdgcn_mfma_f32_16x16x32_bf16(a, b, acc, 0, 0, 0);
        }
        if (et < 4) {
#pragma unroll
            for (int j = 0; j < 4; ++j) {
                const int d = wv * 16 + quad * 4 + j;
                So[d * DVv + et * 16 + col] = acc[j];
            }
        } else if (col == 0) {
#pragma unroll
            for (int j = 0; j < 4; ++j) {
                const int d = wv * 16 + quad * 4 + j;
                zws[hc * Dd + d] = acc[j];
            }
        }
    }
}

// ---------------- Phase 2: exclusive prefix over chunk axis (load-all-then-scan).
__global__ __launch_bounds__(256) void k_prefix(
    float* __restrict__ Sws, float* __restrict__ zws)
{
    const int idx = blockIdx.x * 256 + threadIdx.x;   // [0, 65536) = 16 heads x 4096
    const int h  = idx >> 12;
    const int el = idx & 4095;
    float* base = Sws + ((size_t)h * Cc) * (Dd * DVv) + el;
    float v[Cc];
#pragma unroll
    for (int c = 0; c < Cc; ++c) v[c] = base[c * (Dd * DVv)];
    float run = 0.0f;
#pragma unroll
    for (int c = 0; c < Cc; ++c) { base[c * (Dd * DVv)] = run; run += v[c]; }
    if (idx < Hh * Dd) {
        const int zh = idx >> 6, zd = idx & 63;
        float* zb = zws + zh * Cc * Dd + zd;
        float zv[Cc];
#pragma unroll
        for (int c = 0; c < Cc; ++c) zv[c] = zb[c * Dd];
        float zr = 0.0f;
#pragma unroll
        for (int c = 0; c < Cc; ++c) { zb[c * Dd] = zr; zr += zv[c]; }
    }
}

// ---------------- Phase 3: W = Qf Kf^T (masked), O = Wm V + Qf S_pre,
//                  den fused as extra B^T row (ones / z_pre). All MFMA.
__global__ __launch_bounds__(256) void k_output(
    const float* __restrict__ Qg, const float* __restrict__ Kg,
    const float* __restrict__ Vg, const float* __restrict__ Spre,
    const float* __restrict__ zpre, float* __restrict__ Og)
{
    __shared__ __align__(16) __bf16 aQ[Ll][LDP];    // Qf row-major (A)
    __shared__ __align__(16) __bf16 aK[Ll][LDP];    // Kf row-major (B^T for W-GEMM)
    __shared__ __align__(16) __bf16 aW[Ll][LDP];    // masked W row-major (A for O-GEMM)
    __shared__ __align__(16) __bf16 bV[80][LDP];    // V^T; row 64 = ones
    __shared__ __align__(16) __bf16 bS[80][LDP];    // Spre^T; row 64 = z_pre
    const int t  = threadIdx.x;
    const int hc = blockIdx.x;
    const float4* Q4 = (const float4*)(Qg + (size_t)hc * (Ll * Dd));
    const float4* K4 = (const float4*)(Kg + (size_t)hc * (Ll * Dd));
    const float4* V4 = (const float4*)(Vg + (size_t)hc * (Ll * DVv));
    const float4* S4 = (const float4*)(Spre + (size_t)hc * (Dd * DVv));
    const float*  zp = zpre + hc * Dd;

    for (int i = t; i < (Ll * Dd) / 4; i += 256) {
        float4 q4 = Q4[i];
        float4 k4 = K4[i];
        float4 v4 = V4[i];
        float4 s4 = S4[i];
        const int m  = i >> 4;         // row of Q/K/V, d-row of S
        const int c0 = (i & 15) * 4;   // col base
        aQ[m][c0 + 0] = tobf(fmap(q4.x));
        aQ[m][c0 + 1] = tobf(fmap(q4.y));
        aQ[m][c0 + 2] = tobf(fmap(q4.z));
        aQ[m][c0 + 3] = tobf(fmap(q4.w));
        aK[m][c0 + 0] = tobf(fmap(k4.x));
        aK[m][c0 + 1] = tobf(fmap(k4.y));
        aK[m][c0 + 2] = tobf(fmap(k4.z));
        aK[m][c0 + 3] = tobf(fmap(k4.w));
        bV[c0 + 0][m] = tobf(v4.x);
        bV[c0 + 1][m] = tobf(v4.y);
        bV[c0 + 2][m] = tobf(v4.z);
        bV[c0 + 3][m] = tobf(v4.w);
        bS[c0 + 0][m] = tobf(s4.x);
        bS[c0 + 1][m] = tobf(s4.y);
        bS[c0 + 2][m] = tobf(s4.z);
        bS[c0 + 3][m] = tobf(s4.w);
    }
    for (int i = t; i < 16 * LDP; i += 256) {        // aux rows
        const int r = i / LDP, c = i % LDP;
        bV[64 + r][c] = (r == 0) ? (__bf16)1.0f : (__bf16)0.0f;
        bS[64 + r][c] = (r == 0 && c < Dd) ? tobf(zp[c]) : (__bf16)0.0f;
    }
    __syncthreads();

    const int lane = t & 63, wv = t >> 6;
    const int col = lane & 15, quad = lane >> 4;

    // W-GEMM: wave wv -> rows n in [wv*16, wv*16+16), all 4 m-tiles
#pragma unroll 1
    for (int mt = 0; mt < 4; ++mt) {
        f32x4 wacc = {0.f, 0.f, 0.f, 0.f};
#pragma unroll
        for (int ks = 0; ks < 2; ++ks) {
            bf16x8 a = *(const bf16x8*)&aQ[wv * 16 + col][ks * 32 + quad * 8];
            bf16x8 b = *(const bf16x8*)&aK[mt * 16 + col][ks * 32 + quad * 8];
            wacc = __builtin_amdgcn_mfma_f32_16x16x32_bf16(a, b, wacc, 0, 0, 0);
        }
#pragma unroll
        for (int j = 0; j < 4; ++j) {
            const int n = wv * 16 + quad * 4 + j;
            const int m = mt * 16 + col;
            aW[n][m] = tobf(m <= n ? wacc[j] : 0.0f);   // causal mask
        }
    }
    __syncthreads();

    // O-GEMM: acc[et] = Wm.V^T-part + Qf.Spre-part; et=4 is the den column
    f32x4 accs[5];
#pragma unroll 1
    for (int et = 0; et < 5; ++et) {
        f32x4 acc = {0.f, 0.f, 0.f, 0.f};
#pragma unroll
        for (int ks = 0; ks < 2; ++ks) {
            bf16x8 a = *(const bf16x8*)&aW[wv * 16 + col][ks * 32 + quad * 8];
            bf16x8 b = *(const bf16x8*)&bV[et * 16 + col][ks * 32 + quad * 8];
            acc = __builtin_amdgcn_mfma_f32_16x16x32_bf16(a, b, acc, 0, 0, 0);
        }
#pragma unroll
        for (int ks = 0; ks < 2; ++ks) {
            bf16x8 a = *(const bf16x8*)&aQ[wv * 16 + col][ks * 32 + quad * 8];
            bf16x8 b = *(const bf16x8*)&bS[et * 16 + col][ks * 32 + quad * 8];
            acc = __builtin_amdgcn_mfma_f32_16x16x32_bf16(a, b, acc, 0, 0, 0);
        }
        accs[et] = acc;
    }
    // den for this lane's 4 rows lives in lane quad*16 of the et=4 tile (col 0)
    float dn[4];
#pragma unroll
    for (int j = 0; j < 4; ++j) dn[j] = __shfl(accs[4][j], lane & 48);

    float* Oc = Og + (size_t)hc * (Ll * DVv);
#pragma unroll
    for (int et = 0; et < 4; ++et) {
#pragma unroll
        for (int j = 0; j < 4; ++j) {
            const int n = wv * 16 + quad * 4 + j;
            Oc[n * DVv + et * 16 + col] = accs[et][j] / (dn[j] + EPSf);
        }
    }
}

extern "C" void kernel_launch(void* const* d_in, const int* in_sizes, int n_in,
                              void* d_out, int out_size, void* d_ws, size_t ws_size,
                              hipStream_t stream) {
    const float* Q = (const float*)d_in[0];
    const float* K = (const float*)d_in[1];
    const float* V = (const float*)d_in[2];
    float* Sws = (float*)d_ws;                          // HC * 64*64 f32 = 8 MB
    float* zws = Sws + (size_t)HCc * Dd * DVv;          // HC * 64 f32
    float* out = (float*)d_out;

    k_chunk_sums<<<HCc, 256, 0, stream>>>(K, V, Sws, zws);
    k_prefix<<<(Hh * Dd * DVv) / 256, 256, 0, stream>>>(Sws, zws);
    k_output<<<HCc, 256, 0, stream>>>(Q, K, V, Sws, zws, out);
}